// Round 6
// baseline (2224.151 us; speedup 1.0000x reference)
//
#include <hip/hip_runtime.h>
#include <cstdint>
#include <cstddef>

#define N_NODES 12288
#define D_FEAT  256
#define K_TOP   31

// np-f32 elementwise chain: g = relu(x*w0)*w1, IEEE f32 per op, no contraction.
__device__ __forceinline__ float np_g(float xv, float w0v, float w1v) {
  #pragma clang fp contract(off)
  float t = __fmul_rn(xv, w0v);
  t = fmaxf(t, 0.0f);
  return __fmul_rn(t, w1v);
}

// ---------------------------------------------------------------------------
// Kernel 1: norm[n] = max(sqrt(np.sum(h*h, -1)), 1e-12), replicating numpy's
// FLOAT_pairwise_sum for n=256: pw(a,256)=pw(a,128)+pw(a+128,128); base(128)=
// scalar 8-accumulator loop, combine ((r0+r1)+(r2+r3))+((r4+r5)+(r6+r7)).
// One thread per row.
// ---------------------------------------------------------------------------
__global__ __launch_bounds__(256) void np_norm_kernel(
    const float* __restrict__ x, const float* __restrict__ w0,
    const float* __restrict__ w1, float* __restrict__ nrm) {
  #pragma clang fp contract(off)
  const int n = blockIdx.x * blockDim.x + threadIdx.x;
  if (n >= N_NODES) return;
  const float* xr = x + (size_t)n * D_FEAT;
  float blk[2];
  #pragma unroll
  for (int b = 0; b < 2; ++b) {
    float r[8];
    #pragma unroll
    for (int j = 0; j < 8; ++j) {
      const int d = 128 * b + j;
      const float g = np_g(xr[d], w0[d], w1[d]);
      r[j] = __fmul_rn(g, g);
    }
    for (int i = 8; i < 128; i += 8) {
      #pragma unroll
      for (int j = 0; j < 8; ++j) {
        const int d = 128 * b + i + j;
        const float g = np_g(xr[d], w0[d], w1[d]);
        r[j] = __fadd_rn(r[j], __fmul_rn(g, g));
      }
    }
    blk[b] = __fadd_rn(
        __fadd_rn(__fadd_rn(r[0], r[1]), __fadd_rn(r[2], r[3])),
        __fadd_rn(__fadd_rn(r[4], r[5]), __fadd_rn(r[6], r[7])));
  }
  const float tot = __fadd_rn(blk[0], blk[1]);
  nrm[n] = fmaxf(__fsqrt_rn(tot), 1e-12f);
}

// ---------------------------------------------------------------------------
// Kernel 2: s[n,m] replicating a BLAS sgemm accumulation (OpenBLAS microkernel
// semantics): ONE f32 accumulator per output element, ascending k, fused FMA:
//   acc = 0; for d = 0..255: acc = fmaf(h_n[d], h_m[d], acc)
// h = g / norm with IEEE f32 divide. 64x64 tile, 256 threads, 4x4 per thread,
// k staged in 32-wide LDS chunks (row-major, +4 pad), float4 reads along d.
// ---------------------------------------------------------------------------
#define BT 64
#define BK 32

__global__ __launch_bounds__(256) void np_gemm_kernel(
    const float* __restrict__ x, const float* __restrict__ w0,
    const float* __restrict__ w1, const float* __restrict__ nrm,
    float* __restrict__ out) {
  #pragma clang fp contract(off)
  __shared__ float As[BT][BK + 4];  // stride 36 floats: 16B-aligned, bank-spread
  __shared__ float Bs[BT][BK + 4];

  const int n0 = blockIdx.y * BT;
  const int m0 = blockIdx.x * BT;
  const int t = threadIdx.x;
  const int tx = t & 15, ty = t >> 4;   // 16x16 thread grid, 4x4 outputs each
  const int sr = t >> 2;                // staging row 0..63
  const int sc = (t & 3) * 8;           // staging col offset 0,8,16,24

  float acc[4][4] = {};

  for (int k0 = 0; k0 < D_FEAT; k0 += BK) {
    __syncthreads();  // protect previous chunk's LDS reads
    {
      const float ia = nrm[n0 + sr];
      const float ib = nrm[m0 + sr];
      #pragma unroll
      for (int h = 0; h < 2; ++h) {
        const int c = sc + h * 4;
        const float4 xa = *reinterpret_cast<const float4*>(
            &x[(size_t)(n0 + sr) * D_FEAT + k0 + c]);
        const float4 xb = *reinterpret_cast<const float4*>(
            &x[(size_t)(m0 + sr) * D_FEAT + k0 + c]);
        const float4 wa = *reinterpret_cast<const float4*>(&w0[k0 + c]);
        const float4 wb = *reinterpret_cast<const float4*>(&w1[k0 + c]);
        const float xaf[4] = {xa.x, xa.y, xa.z, xa.w};
        const float xbf[4] = {xb.x, xb.y, xb.z, xb.w};
        const float w0f[4] = {wa.x, wa.y, wa.z, wa.w};
        const float w1f[4] = {wb.x, wb.y, wb.z, wb.w};
        #pragma unroll
        for (int e = 0; e < 4; ++e) {
          As[sr][c + e] = __fdiv_rn(np_g(xaf[e], w0f[e], w1f[e]), ia);
          Bs[sr][c + e] = __fdiv_rn(np_g(xbf[e], w0f[e], w1f[e]), ib);
        }
      }
    }
    __syncthreads();

    for (int d0 = 0; d0 < BK; d0 += 4) {
      float4 a4[4], b4[4];
      #pragma unroll
      for (int i = 0; i < 4; ++i)
        a4[i] = *reinterpret_cast<const float4*>(&As[ty * 4 + i][d0]);
      #pragma unroll
      for (int j = 0; j < 4; ++j)
        b4[j] = *reinterpret_cast<const float4*>(&Bs[tx * 4 + j][d0]);
      const float af[4][4] = {
          {a4[0].x, a4[0].y, a4[0].z, a4[0].w},
          {a4[1].x, a4[1].y, a4[1].z, a4[1].w},
          {a4[2].x, a4[2].y, a4[2].z, a4[2].w},
          {a4[3].x, a4[3].y, a4[3].z, a4[3].w}};
      const float bf[4][4] = {
          {b4[0].x, b4[0].y, b4[0].z, b4[0].w},
          {b4[1].x, b4[1].y, b4[1].z, b4[1].w},
          {b4[2].x, b4[2].y, b4[2].z, b4[2].w},
          {b4[3].x, b4[3].y, b4[3].z, b4[3].w}};
      // Ascending d, single fused-FMA chain per output element.
      #pragma unroll
      for (int dd = 0; dd < 4; ++dd)
        #pragma unroll
        for (int i = 0; i < 4; ++i)
          #pragma unroll
          for (int j = 0; j < 4; ++j)
            acc[i][j] = __builtin_fmaf(af[i][dd], bf[j][dd], acc[i][j]);
    }
  }

  #pragma unroll
  for (int i = 0; i < 4; ++i) {
    float4 o;
    o.x = acc[i][0]; o.y = acc[i][1]; o.z = acc[i][2]; o.w = acc[i][3];
    *reinterpret_cast<float4*>(
        &out[(size_t)(n0 + ty * 4 + i) * N_NODES + m0 + tx * 4]) = o;
  }
}

// ---------------------------------------------------------------------------
// Kernel 3: per-row top-K mask + relu on the f32 s. Boundary ties kept
// lowest-index-first (jax.lax.top_k stable semantics).
// ---------------------------------------------------------------------------
__device__ inline float att_decode(unsigned uu) {
  return (uu & 0x80000000u) ? __uint_as_float(uu & 0x7FFFFFFFu)
                            : __uint_as_float(~uu);
}

__global__ __launch_bounds__(256) void att_topk_kernel(float* __restrict__ s) {
  const int n = blockIdx.x;
  float* row = s + (size_t)n * N_NODES;
  const int t = threadIdx.x;

  unsigned u[48];
#pragma unroll
  for (int i = 0; i < 12; ++i) {
    float4 v = reinterpret_cast<const float4*>(row)[t + 256 * i];
    const float f[4] = {v.x, v.y, v.z, v.w};
#pragma unroll
    for (int j = 0; j < 4; ++j) {
      unsigned b = __float_as_uint(f[j]);
      u[i * 4 + j] = (b & 0x80000000u) ? ~b : (b | 0x80000000u);
    }
  }

  __shared__ int cnt_s;

  unsigned lo = 0u, hi = 0xFFFFFFFFu;
  while (hi - lo > 1u) {
    const unsigned mid = lo + ((hi - lo) >> 1);
    int c = 0;
#pragma unroll
    for (int i = 0; i < 48; ++i) c += (u[i] >= mid) ? 1 : 0;
#pragma unroll
    for (int o = 32; o > 0; o >>= 1) c += __shfl_down(c, o);
    if (t == 0) cnt_s = 0;
    __syncthreads();
    if ((t & 63) == 0) atomicAdd(&cnt_s, c);
    __syncthreads();
    const int total = cnt_s;
    __syncthreads();
    if (total >= K_TOP) lo = mid; else hi = mid;
  }
  const unsigned T = lo;

  {
    int cg = 0, ce = 0;
#pragma unroll
    for (int i = 0; i < 48; ++i) {
      cg += (u[i] > T) ? 1 : 0;
      ce += (u[i] == T) ? 1 : 0;
    }
    int packed = (cg << 16) | ce;
#pragma unroll
    for (int o = 32; o > 0; o >>= 1) packed += __shfl_down(packed, o);
    if (t == 0) cnt_s = 0;
    __syncthreads();
    if ((t & 63) == 0) atomicAdd(&cnt_s, packed);
    __syncthreads();
  }
  const int tot = cnt_s;
  __syncthreads();
  const int tot_gt = tot >> 16;
  const int tot_eq = tot & 0xFFFF;
  const int need = K_TOP - tot_gt;

  if (tot_eq == need) {
#pragma unroll
    for (int i = 0; i < 12; ++i) {
      float vals[4];
#pragma unroll
      for (int j = 0; j < 4; ++j) {
        const unsigned uu = u[i * 4 + j];
        const float f = att_decode(uu);
        vals[j] = (uu >= T) ? fmaxf(f, 0.0f) : 0.0f;
      }
      float4 o; o.x = vals[0]; o.y = vals[1]; o.z = vals[2]; o.w = vals[3];
      reinterpret_cast<float4*>(row)[t + 256 * i] = o;
    }
  } else {
    __shared__ int eqc[12][256];
#pragma unroll
    for (int i = 0; i < 12; ++i) {
      int c = 0;
#pragma unroll
      for (int j = 0; j < 4; ++j) c += (u[i * 4 + j] == T) ? 1 : 0;
      eqc[i][t] = c;
    }
    __syncthreads();
    int base[12];
    {
      int run = 0;
      for (int i = 0; i < 12; ++i) {
        int pre = 0, tt_tot = 0;
        for (int tt = 0; tt < 256; ++tt) {
          const int v = eqc[i][tt];
          if (tt < t) pre += v;
          tt_tot += v;
        }
        base[i] = run + pre;
        run += tt_tot;
      }
    }
#pragma unroll
    for (int i = 0; i < 12; ++i) {
      float vals[4];
      int r = base[i];
#pragma unroll
      for (int j = 0; j < 4; ++j) {
        const unsigned uu = u[i * 4 + j];
        const float f = att_decode(uu);
        bool keep = false;
        if (uu > T) keep = true;
        else if (uu == T) { keep = (r < need); ++r; }
        vals[j] = keep ? fmaxf(f, 0.0f) : 0.0f;
      }
      float4 o; o.x = vals[0]; o.y = vals[1]; o.z = vals[2]; o.w = vals[3];
      reinterpret_cast<float4*>(row)[t + 256 * i] = o;
    }
  }
}

// ---------------------------------------------------------------------------
extern "C" void kernel_launch(void* const* d_in, const int* in_sizes, int n_in,
                              void* d_out, int out_size, void* d_ws, size_t ws_size,
                              hipStream_t stream) {
  const float* x  = (const float*)d_in[0];
  const float* w0 = (const float*)d_in[1];
  const float* w1 = (const float*)d_in[2];
  float* out = (float*)d_out;
  float* nrm = (float*)d_ws;  // 48 KiB scratch

  np_norm_kernel<<<N_NODES / 256, 256, 0, stream>>>(x, w0, w1, nrm);

  dim3 grid(N_NODES / BT, N_NODES / BT);  // 192 x 192
  np_gemm_kernel<<<grid, 256, 0, stream>>>(x, w0, w1, nrm, out);

  att_topk_kernel<<<N_NODES, 256, 0, stream>>>(out);
}

// Round 7
// 1770.615 us; speedup vs baseline: 1.2561x; 1.2561x over previous
//
#include <hip/hip_runtime.h>
#include <cstdint>
#include <cstddef>

#define N_NODES 12288
#define D_FEAT  256
#define K_TOP   31

// np-f32 elementwise chain: g = relu(x*w0)*w1, IEEE f32 per op, no contraction.
__device__ __forceinline__ float np_g(float xv, float w0v, float w1v) {
  #pragma clang fp contract(off)
  float t = __fmul_rn(xv, w0v);
  t = fmaxf(t, 0.0f);
  return __fmul_rn(t, w1v);
}

// ---------------------------------------------------------------------------
// Kernel 1 (unchanged from r6): norm[n] = max(sqrt(np.sum(h*h, -1)), 1e-12),
// replicating numpy FLOAT_pairwise_sum for n=256 (scalar 8-accumulator base).
// ---------------------------------------------------------------------------
__global__ __launch_bounds__(256) void np_norm_kernel(
    const float* __restrict__ x, const float* __restrict__ w0,
    const float* __restrict__ w1, float* __restrict__ nrm) {
  #pragma clang fp contract(off)
  const int n = blockIdx.x * blockDim.x + threadIdx.x;
  if (n >= N_NODES) return;
  const float* xr = x + (size_t)n * D_FEAT;
  float blk[2];
  #pragma unroll
  for (int b = 0; b < 2; ++b) {
    float r[8];
    #pragma unroll
    for (int j = 0; j < 8; ++j) {
      const int d = 128 * b + j;
      const float g = np_g(xr[d], w0[d], w1[d]);
      r[j] = __fmul_rn(g, g);
    }
    for (int i = 8; i < 128; i += 8) {
      #pragma unroll
      for (int j = 0; j < 8; ++j) {
        const int d = 128 * b + i + j;
        const float g = np_g(xr[d], w0[d], w1[d]);
        r[j] = __fadd_rn(r[j], __fmul_rn(g, g));
      }
    }
    blk[b] = __fadd_rn(
        __fadd_rn(__fadd_rn(r[0], r[1]), __fadd_rn(r[2], r[3])),
        __fadd_rn(__fadd_rn(r[4], r[5]), __fadd_rn(r[6], r[7])));
  }
  const float tot = __fadd_rn(blk[0], blk[1]);
  nrm[n] = fmaxf(__fsqrt_rn(tot), 1e-12f);
}

// ---------------------------------------------------------------------------
// Kernel 2: BLAS-chain GEMM, restructured for LDS efficiency.
// Arithmetic per output element is BIT-IDENTICAL to round 6:
//   acc = 0; for d = 0..255 ascending: acc = fmaf(h_n[d], h_m[d], acc)
// Layout: 128x128 tile, BK=32, 256 threads, 8x8 outputs per thread via
// {base, base+64} row/col split. k-major LDS As[BK][BT]:
//   A-frag reads conflict-free (4 distinct b128 addrs/wave, 16-lane bcast),
//   B-frag reads 2-way (free), staging writes 2-way (free).
// ---------------------------------------------------------------------------
#define BT 128
#define BK 32

__global__ __launch_bounds__(256, 4) void np_gemm_kernel(
    const float* __restrict__ x, const float* __restrict__ w0,
    const float* __restrict__ w1, const float* __restrict__ nrm,
    float* __restrict__ out) {
  #pragma clang fp contract(off)
  __shared__ float As[BK][BT];
  __shared__ float Bs[BK][BT];

  const int n0 = blockIdx.y * BT;
  const int m0 = blockIdx.x * BT;
  const int t = threadIdx.x;
  const int tx = t & 15, ty = t >> 4;  // 16x16 thread grid
  const int sr = t >> 1;               // staging row 0..127
  const int sk = (t & 1) * 16;         // staging k offset 0 or 16

  float acc[8][8] = {};  // [i: rowgrp*4 + r][j: colgrp*4 + c]

  for (int k0 = 0; k0 < D_FEAT; k0 += BK) {
    __syncthreads();  // protect previous chunk's LDS reads
    {
      const float ia = nrm[n0 + sr];
      const float ib = nrm[m0 + sr];
      #pragma unroll
      for (int q = 0; q < 4; ++q) {
        const int c = sk + q * 4;
        const float4 xa = *reinterpret_cast<const float4*>(
            &x[(size_t)(n0 + sr) * D_FEAT + k0 + c]);
        const float4 xb = *reinterpret_cast<const float4*>(
            &x[(size_t)(m0 + sr) * D_FEAT + k0 + c]);
        const float4 wa = *reinterpret_cast<const float4*>(&w0[k0 + c]);
        const float4 wb = *reinterpret_cast<const float4*>(&w1[k0 + c]);
        const float xaf[4] = {xa.x, xa.y, xa.z, xa.w};
        const float xbf[4] = {xb.x, xb.y, xb.z, xb.w};
        const float w0f[4] = {wa.x, wa.y, wa.z, wa.w};
        const float w1f[4] = {wb.x, wb.y, wb.z, wb.w};
        #pragma unroll
        for (int e = 0; e < 4; ++e) {
          As[c + e][sr] = __fdiv_rn(np_g(xaf[e], w0f[e], w1f[e]), ia);
          Bs[c + e][sr] = __fdiv_rn(np_g(xbf[e], w0f[e], w1f[e]), ib);
        }
      }
    }
    __syncthreads();

    for (int kk = 0; kk < BK; ++kk) {
      const float4 a0 = *reinterpret_cast<const float4*>(&As[kk][ty * 4]);
      const float4 a1 = *reinterpret_cast<const float4*>(&As[kk][64 + ty * 4]);
      const float4 b0 = *reinterpret_cast<const float4*>(&Bs[kk][tx * 4]);
      const float4 b1 = *reinterpret_cast<const float4*>(&Bs[kk][64 + tx * 4]);
      const float af[8] = {a0.x, a0.y, a0.z, a0.w, a1.x, a1.y, a1.z, a1.w};
      const float bf[8] = {b0.x, b0.y, b0.z, b0.w, b1.x, b1.y, b1.z, b1.w};
      #pragma unroll
      for (int i = 0; i < 8; ++i)
        #pragma unroll
        for (int j = 0; j < 8; ++j)
          acc[i][j] = __builtin_fmaf(af[i], bf[j], acc[i][j]);
    }
  }

  #pragma unroll
  for (int i = 0; i < 8; ++i) {
    const int row = n0 + (i >> 2) * 64 + ty * 4 + (i & 3);
    float4 o0, o1;
    o0.x = acc[i][0]; o0.y = acc[i][1]; o0.z = acc[i][2]; o0.w = acc[i][3];
    o1.x = acc[i][4]; o1.y = acc[i][5]; o1.z = acc[i][6]; o1.w = acc[i][7];
    *reinterpret_cast<float4*>(&out[(size_t)row * N_NODES + m0 + tx * 4]) = o0;
    *reinterpret_cast<float4*>(&out[(size_t)row * N_NODES + m0 + 64 + tx * 4]) = o1;
  }
}

// ---------------------------------------------------------------------------
// Kernel 3 (unchanged from r6): per-row top-K mask + relu on the f32 s.
// Boundary ties kept lowest-index-first.
// ---------------------------------------------------------------------------
__device__ inline float att_decode(unsigned uu) {
  return (uu & 0x80000000u) ? __uint_as_float(uu & 0x7FFFFFFFu)
                            : __uint_as_float(~uu);
}

__global__ __launch_bounds__(256) void att_topk_kernel(float* __restrict__ s) {
  const int n = blockIdx.x;
  float* row = s + (size_t)n * N_NODES;
  const int t = threadIdx.x;

  unsigned u[48];
#pragma unroll
  for (int i = 0; i < 12; ++i) {
    float4 v = reinterpret_cast<const float4*>(row)[t + 256 * i];
    const float f[4] = {v.x, v.y, v.z, v.w};
#pragma unroll
    for (int j = 0; j < 4; ++j) {
      unsigned b = __float_as_uint(f[j]);
      u[i * 4 + j] = (b & 0x80000000u) ? ~b : (b | 0x80000000u);
    }
  }

  __shared__ int cnt_s;

  unsigned lo = 0u, hi = 0xFFFFFFFFu;
  while (hi - lo > 1u) {
    const unsigned mid = lo + ((hi - lo) >> 1);
    int c = 0;
#pragma unroll
    for (int i = 0; i < 48; ++i) c += (u[i] >= mid) ? 1 : 0;
#pragma unroll
    for (int o = 32; o > 0; o >>= 1) c += __shfl_down(c, o);
    if (t == 0) cnt_s = 0;
    __syncthreads();
    if ((t & 63) == 0) atomicAdd(&cnt_s, c);
    __syncthreads();
    const int total = cnt_s;
    __syncthreads();
    if (total >= K_TOP) lo = mid; else hi = mid;
  }
  const unsigned T = lo;

  {
    int cg = 0, ce = 0;
#pragma unroll
    for (int i = 0; i < 48; ++i) {
      cg += (u[i] > T) ? 1 : 0;
      ce += (u[i] == T) ? 1 : 0;
    }
    int packed = (cg << 16) | ce;
#pragma unroll
    for (int o = 32; o > 0; o >>= 1) packed += __shfl_down(packed, o);
    if (t == 0) cnt_s = 0;
    __syncthreads();
    if ((t & 63) == 0) atomicAdd(&cnt_s, packed);
    __syncthreads();
  }
  const int tot = cnt_s;
  __syncthreads();
  const int tot_gt = tot >> 16;
  const int tot_eq = tot & 0xFFFF;
  const int need = K_TOP - tot_gt;

  if (tot_eq == need) {
#pragma unroll
    for (int i = 0; i < 12; ++i) {
      float vals[4];
#pragma unroll
      for (int j = 0; j < 4; ++j) {
        const unsigned uu = u[i * 4 + j];
        const float f = att_decode(uu);
        vals[j] = (uu >= T) ? fmaxf(f, 0.0f) : 0.0f;
      }
      float4 o; o.x = vals[0]; o.y = vals[1]; o.z = vals[2]; o.w = vals[3];
      reinterpret_cast<float4*>(row)[t + 256 * i] = o;
    }
  } else {
    __shared__ int eqc[12][256];
#pragma unroll
    for (int i = 0; i < 12; ++i) {
      int c = 0;
#pragma unroll
      for (int j = 0; j < 4; ++j) c += (u[i * 4 + j] == T) ? 1 : 0;
      eqc[i][t] = c;
    }
    __syncthreads();
    int base[12];
    {
      int run = 0;
      for (int i = 0; i < 12; ++i) {
        int pre = 0, tt_tot = 0;
        for (int tt = 0; tt < 256; ++tt) {
          const int v = eqc[i][tt];
          if (tt < t) pre += v;
          tt_tot += v;
        }
        base[i] = run + pre;
        run += tt_tot;
      }
    }
#pragma unroll
    for (int i = 0; i < 12; ++i) {
      float vals[4];
      int r = base[i];
#pragma unroll
      for (int j = 0; j < 4; ++j) {
        const unsigned uu = u[i * 4 + j];
        const float f = att_decode(uu);
        bool keep = false;
        if (uu > T) keep = true;
        else if (uu == T) { keep = (r < need); ++r; }
        vals[j] = keep ? fmaxf(f, 0.0f) : 0.0f;
      }
      float4 o; o.x = vals[0]; o.y = vals[1]; o.z = vals[2]; o.w = vals[3];
      reinterpret_cast<float4*>(row)[t + 256 * i] = o;
    }
  }
}

// ---------------------------------------------------------------------------
extern "C" void kernel_launch(void* const* d_in, const int* in_sizes, int n_in,
                              void* d_out, int out_size, void* d_ws, size_t ws_size,
                              hipStream_t stream) {
  const float* x  = (const float*)d_in[0];
  const float* w0 = (const float*)d_in[1];
  const float* w1 = (const float*)d_in[2];
  float* out = (float*)d_out;
  float* nrm = (float*)d_ws;  // 48 KiB scratch

  np_norm_kernel<<<N_NODES / 256, 256, 0, stream>>>(x, w0, w1, nrm);

  dim3 grid(N_NODES / BT, N_NODES / BT);  // 96 x 96
  np_gemm_kernel<<<grid, 256, 0, stream>>>(x, w0, w1, nrm, out);

  att_topk_kernel<<<N_NODES, 256, 0, stream>>>(out);
}

// Round 8
// 1268.325 us; speedup vs baseline: 1.7536x; 1.3960x over previous
//
#include <hip/hip_runtime.h>
#include <cstdint>
#include <cstddef>
#include <math.h>

#define N_NODES 12288
#define D_FEAT  256
#define K_TOP   31

// np-f32 elementwise chain: g = relu(x*w0)*w1, IEEE f32 per op, no contraction.
__device__ __forceinline__ float np_g(float xv, float w0v, float w1v) {
  #pragma clang fp contract(off)
  float t = __fmul_rn(xv, w0v);
  t = fmaxf(t, 0.0f);
  return __fmul_rn(t, w1v);
}

// ---------------------------------------------------------------------------
// Kernel 1 (unchanged): norm[n] = max(sqrt(np.sum(h*h, -1)), 1e-12),
// replicating numpy FLOAT_pairwise_sum for n=256 (scalar 8-accumulator base).
// ---------------------------------------------------------------------------
__global__ __launch_bounds__(256) void np_norm_kernel(
    const float* __restrict__ x, const float* __restrict__ w0,
    const float* __restrict__ w1, float* __restrict__ nrm) {
  #pragma clang fp contract(off)
  const int n = blockIdx.x * blockDim.x + threadIdx.x;
  if (n >= N_NODES) return;
  const float* xr = x + (size_t)n * D_FEAT;
  float blk[2];
  #pragma unroll
  for (int b = 0; b < 2; ++b) {
    float r[8];
    #pragma unroll
    for (int j = 0; j < 8; ++j) {
      const int d = 128 * b + j;
      const float g = np_g(xr[d], w0[d], w1[d]);
      r[j] = __fmul_rn(g, g);
    }
    for (int i = 8; i < 128; i += 8) {
      #pragma unroll
      for (int j = 0; j < 8; ++j) {
        const int d = 128 * b + i + j;
        const float g = np_g(xr[d], w0[d], w1[d]);
        r[j] = __fadd_rn(r[j], __fmul_rn(g, g));
      }
    }
    blk[b] = __fadd_rn(
        __fadd_rn(__fadd_rn(r[0], r[1]), __fadd_rn(r[2], r[3])),
        __fadd_rn(__fadd_rn(r[4], r[5]), __fadd_rn(r[6], r[7])));
  }
  const float tot = __fadd_rn(blk[0], blk[1]);
  nrm[n] = fmaxf(__fsqrt_rn(tot), 1e-12f);
}

// ---------------------------------------------------------------------------
// Kernel 2: BLAS-chain GEMM, SYMMETRIC-HALF version.
// Arithmetic per output element is BIT-IDENTICAL to rounds 6/7:
//   acc = 0; for d = 0..255 ascending: acc = fmaf(h_n[d], h_m[d], acc)
// s is bitwise symmetric (IEEE mul/fma commute in their first two operands),
// so only upper-triangle 128x128 tiles are computed (4656 blocks); off-
// diagonal tiles are stored twice (direct + transposed, both float4-wise).
// k-major LDS As[BK][BT]: A-frag reads broadcast, B-frag/staging 2-way free.
// ---------------------------------------------------------------------------
#define BT 128
#define BK 32
#define NTILES (N_NODES / BT)              // 96
#define NBLOCKS (NTILES * (NTILES + 1) / 2)  // 4656

__global__ __launch_bounds__(256, 4) void np_gemm_kernel(
    const float* __restrict__ x, const float* __restrict__ w0,
    const float* __restrict__ w1, const float* __restrict__ nrm,
    float* __restrict__ out) {
  #pragma clang fp contract(off)
  __shared__ float As[BK][BT];
  __shared__ float Bs[BK][BT];

  // Decode linear block id -> upper-triangle (by, bx), bx >= by.
  const int L = blockIdx.x;
  int by = (int)(96.5 - sqrt(96.5 * 96.5 - 2.0 * (double)L));
  while (by > 0 && by * NTILES - by * (by - 1) / 2 > L) --by;
  while ((by + 1) * NTILES - (by + 1) * by / 2 <= L) ++by;
  const int bx = by + (L - (by * NTILES - by * (by - 1) / 2));

  const int n0 = by * BT;
  const int m0 = bx * BT;
  const int t = threadIdx.x;
  const int tx = t & 15, ty = t >> 4;  // 16x16 thread grid
  const int sr = t >> 1;               // staging row 0..127
  const int sk = (t & 1) * 16;         // staging k offset 0 or 16

  float acc[8][8] = {};  // [i: rowgrp*64 + ty*4 + r][j: colgrp*64 + tx*4 + c]

  for (int k0 = 0; k0 < D_FEAT; k0 += BK) {
    __syncthreads();  // protect previous chunk's LDS reads
    {
      const float ia = nrm[n0 + sr];
      const float ib = nrm[m0 + sr];
      #pragma unroll
      for (int q = 0; q < 4; ++q) {
        const int c = sk + q * 4;
        const float4 xa = *reinterpret_cast<const float4*>(
            &x[(size_t)(n0 + sr) * D_FEAT + k0 + c]);
        const float4 xb = *reinterpret_cast<const float4*>(
            &x[(size_t)(m0 + sr) * D_FEAT + k0 + c]);
        const float4 wa = *reinterpret_cast<const float4*>(&w0[k0 + c]);
        const float4 wb = *reinterpret_cast<const float4*>(&w1[k0 + c]);
        const float xaf[4] = {xa.x, xa.y, xa.z, xa.w};
        const float xbf[4] = {xb.x, xb.y, xb.z, xb.w};
        const float w0f[4] = {wa.x, wa.y, wa.z, wa.w};
        const float w1f[4] = {wb.x, wb.y, wb.z, wb.w};
        #pragma unroll
        for (int e = 0; e < 4; ++e) {
          As[c + e][sr] = __fdiv_rn(np_g(xaf[e], w0f[e], w1f[e]), ia);
          Bs[c + e][sr] = __fdiv_rn(np_g(xbf[e], w0f[e], w1f[e]), ib);
        }
      }
    }
    __syncthreads();

    for (int kk = 0; kk < BK; ++kk) {
      const float4 a0 = *reinterpret_cast<const float4*>(&As[kk][ty * 4]);
      const float4 a1 = *reinterpret_cast<const float4*>(&As[kk][64 + ty * 4]);
      const float4 b0 = *reinterpret_cast<const float4*>(&Bs[kk][tx * 4]);
      const float4 b1 = *reinterpret_cast<const float4*>(&Bs[kk][64 + tx * 4]);
      const float af[8] = {a0.x, a0.y, a0.z, a0.w, a1.x, a1.y, a1.z, a1.w};
      const float bf[8] = {b0.x, b0.y, b0.z, b0.w, b1.x, b1.y, b1.z, b1.w};
      #pragma unroll
      for (int i = 0; i < 8; ++i)
        #pragma unroll
        for (int j = 0; j < 8; ++j)
          acc[i][j] = __builtin_fmaf(af[i], bf[j], acc[i][j]);
    }
  }

  // Direct tile store: s[n][m].
  #pragma unroll
  for (int i = 0; i < 8; ++i) {
    const int row = n0 + (i >> 2) * 64 + ty * 4 + (i & 3);
    float4 o0, o1;
    o0.x = acc[i][0]; o0.y = acc[i][1]; o0.z = acc[i][2]; o0.w = acc[i][3];
    o1.x = acc[i][4]; o1.y = acc[i][5]; o1.z = acc[i][6]; o1.w = acc[i][7];
    *reinterpret_cast<float4*>(&out[(size_t)row * N_NODES + m0 + tx * 4]) = o0;
    *reinterpret_cast<float4*>(&out[(size_t)row * N_NODES + m0 + 64 + tx * 4]) = o1;
  }

  // Mirror tile store: s[m][n] = s[n][m] (bitwise), off-diagonal blocks only.
  if (bx != by) {
    #pragma unroll
    for (int j = 0; j < 8; ++j) {
      const int mrow = m0 + (j >> 2) * 64 + tx * 4 + (j & 3);
      float4 o0, o1;
      o0.x = acc[0][j]; o0.y = acc[1][j]; o0.z = acc[2][j]; o0.w = acc[3][j];
      o1.x = acc[4][j]; o1.y = acc[5][j]; o1.z = acc[6][j]; o1.w = acc[7][j];
      *reinterpret_cast<float4*>(&out[(size_t)mrow * N_NODES + n0 + ty * 4]) = o0;
      *reinterpret_cast<float4*>(&out[(size_t)mrow * N_NODES + n0 + 64 + ty * 4]) = o1;
    }
  }
}

// ---------------------------------------------------------------------------
// Kernel 3 (unchanged): per-row top-K mask + relu on the f32 s.
// Boundary ties kept lowest-index-first.
// ---------------------------------------------------------------------------
__device__ inline float att_decode(unsigned uu) {
  return (uu & 0x80000000u) ? __uint_as_float(uu & 0x7FFFFFFFu)
                            : __uint_as_float(~uu);
}

__global__ __launch_bounds__(256) void att_topk_kernel(float* __restrict__ s) {
  const int n = blockIdx.x;
  float* row = s + (size_t)n * N_NODES;
  const int t = threadIdx.x;

  unsigned u[48];
#pragma unroll
  for (int i = 0; i < 12; ++i) {
    float4 v = reinterpret_cast<const float4*>(row)[t + 256 * i];
    const float f[4] = {v.x, v.y, v.z, v.w};
#pragma unroll
    for (int j = 0; j < 4; ++j) {
      unsigned b = __float_as_uint(f[j]);
      u[i * 4 + j] = (b & 0x80000000u) ? ~b : (b | 0x80000000u);
    }
  }

  __shared__ int cnt_s;

  unsigned lo = 0u, hi = 0xFFFFFFFFu;
  while (hi - lo > 1u) {
    const unsigned mid = lo + ((hi - lo) >> 1);
    int c = 0;
#pragma unroll
    for (int i = 0; i < 48; ++i) c += (u[i] >= mid) ? 1 : 0;
#pragma unroll
    for (int o = 32; o > 0; o >>= 1) c += __shfl_down(c, o);
    if (t == 0) cnt_s = 0;
    __syncthreads();
    if ((t & 63) == 0) atomicAdd(&cnt_s, c);
    __syncthreads();
    const int total = cnt_s;
    __syncthreads();
    if (total >= K_TOP) lo = mid; else hi = mid;
  }
  const unsigned T = lo;

  {
    int cg = 0, ce = 0;
#pragma unroll
    for (int i = 0; i < 48; ++i) {
      cg += (u[i] > T) ? 1 : 0;
      ce += (u[i] == T) ? 1 : 0;
    }
    int packed = (cg << 16) | ce;
#pragma unroll
    for (int o = 32; o > 0; o >>= 1) packed += __shfl_down(packed, o);
    if (t == 0) cnt_s = 0;
    __syncthreads();
    if ((t & 63) == 0) atomicAdd(&cnt_s, packed);
    __syncthreads();
  }
  const int tot = cnt_s;
  __syncthreads();
  const int tot_gt = tot >> 16;
  const int tot_eq = tot & 0xFFFF;
  const int need = K_TOP - tot_gt;

  if (tot_eq == need) {
#pragma unroll
    for (int i = 0; i < 12; ++i) {
      float vals[4];
#pragma unroll
      for (int j = 0; j < 4; ++j) {
        const unsigned uu = u[i * 4 + j];
        const float f = att_decode(uu);
        vals[j] = (uu >= T) ? fmaxf(f, 0.0f) : 0.0f;
      }
      float4 o; o.x = vals[0]; o.y = vals[1]; o.z = vals[2]; o.w = vals[3];
      reinterpret_cast<float4*>(row)[t + 256 * i] = o;
    }
  } else {
    __shared__ int eqc[12][256];
#pragma unroll
    for (int i = 0; i < 12; ++i) {
      int c = 0;
#pragma unroll
      for (int j = 0; j < 4; ++j) c += (u[i * 4 + j] == T) ? 1 : 0;
      eqc[i][t] = c;
    }
    __syncthreads();
    int base[12];
    {
      int run = 0;
      for (int i = 0; i < 12; ++i) {
        int pre = 0, tt_tot = 0;
        for (int tt = 0; tt < 256; ++tt) {
          const int v = eqc[i][tt];
          if (tt < t) pre += v;
          tt_tot += v;
        }
        base[i] = run + pre;
        run += tt_tot;
      }
    }
#pragma unroll
    for (int i = 0; i < 12; ++i) {
      float vals[4];
      int r = base[i];
#pragma unroll
      for (int j = 0; j < 4; ++j) {
        const unsigned uu = u[i * 4 + j];
        const float f = att_decode(uu);
        bool keep = false;
        if (uu > T) keep = true;
        else if (uu == T) { keep = (r < need); ++r; }
        vals[j] = keep ? fmaxf(f, 0.0f) : 0.0f;
      }
      float4 o; o.x = vals[0]; o.y = vals[1]; o.z = vals[2]; o.w = vals[3];
      reinterpret_cast<float4*>(row)[t + 256 * i] = o;
    }
  }
}

// ---------------------------------------------------------------------------
extern "C" void kernel_launch(void* const* d_in, const int* in_sizes, int n_in,
                              void* d_out, int out_size, void* d_ws, size_t ws_size,
                              hipStream_t stream) {
  const float* x  = (const float*)d_in[0];
  const float* w0 = (const float*)d_in[1];
  const float* w1 = (const float*)d_in[2];
  float* out = (float*)d_out;
  float* nrm = (float*)d_ws;  // 48 KiB scratch

  np_norm_kernel<<<N_NODES / 256, 256, 0, stream>>>(x, w0, w1, nrm);

  np_gemm_kernel<<<NBLOCKS, 256, 0, stream>>>(x, w0, w1, nrm, out);

  att_topk_kernel<<<N_NODES, 256, 0, stream>>>(out);
}

// Round 9
// 881.677 us; speedup vs baseline: 2.5226x; 1.4385x over previous
//
#include <hip/hip_runtime.h>
#include <cstdint>
#include <cstddef>
#include <math.h>

#define N_NODES 12288
#define D_FEAT  256
#define K_TOP   31

// np-f32 elementwise chain: g = relu(x*w0)*w1, IEEE f32 per op, no contraction.
__device__ __forceinline__ float np_g(float xv, float w0v, float w1v) {
  #pragma clang fp contract(off)
  float t = __fmul_rn(xv, w0v);
  t = fmaxf(t, 0.0f);
  return __fmul_rn(t, w1v);
}

// ---------------------------------------------------------------------------
// Kernel 1 (frozen since r6): norm[n] = max(sqrt(np.sum(h*h, -1)), 1e-12),
// replicating numpy FLOAT_pairwise_sum for n=256 (scalar 8-accumulator base).
// ---------------------------------------------------------------------------
__global__ __launch_bounds__(256) void np_norm_kernel(
    const float* __restrict__ x, const float* __restrict__ w0,
    const float* __restrict__ w1, float* __restrict__ nrm) {
  #pragma clang fp contract(off)
  const int n = blockIdx.x * blockDim.x + threadIdx.x;
  if (n >= N_NODES) return;
  const float* xr = x + (size_t)n * D_FEAT;
  float blk[2];
  #pragma unroll
  for (int b = 0; b < 2; ++b) {
    float r[8];
    #pragma unroll
    for (int j = 0; j < 8; ++j) {
      const int d = 128 * b + j;
      const float g = np_g(xr[d], w0[d], w1[d]);
      r[j] = __fmul_rn(g, g);
    }
    for (int i = 8; i < 128; i += 8) {
      #pragma unroll
      for (int j = 0; j < 8; ++j) {
        const int d = 128 * b + i + j;
        const float g = np_g(xr[d], w0[d], w1[d]);
        r[j] = __fadd_rn(r[j], __fmul_rn(g, g));
      }
    }
    blk[b] = __fadd_rn(
        __fadd_rn(__fadd_rn(r[0], r[1]), __fadd_rn(r[2], r[3])),
        __fadd_rn(__fadd_rn(r[4], r[5]), __fadd_rn(r[6], r[7])));
  }
  const float tot = __fadd_rn(blk[0], blk[1]);
  nrm[n] = fmaxf(__fsqrt_rn(tot), 1e-12f);
}

// ---------------------------------------------------------------------------
// Kernel 2 (frozen since r8): symmetric-half BLAS-chain GEMM.
// Per output element bit-identical chain:
//   acc = 0; for d = 0..255 ascending: acc = fmaf(h_n[d], h_m[d], acc)
// ---------------------------------------------------------------------------
#define BT 128
#define BK 32
#define NTILES (N_NODES / BT)                // 96
#define NBLOCKS (NTILES * (NTILES + 1) / 2)  // 4656

__global__ __launch_bounds__(256, 4) void np_gemm_kernel(
    const float* __restrict__ x, const float* __restrict__ w0,
    const float* __restrict__ w1, const float* __restrict__ nrm,
    float* __restrict__ out) {
  #pragma clang fp contract(off)
  __shared__ float As[BK][BT];
  __shared__ float Bs[BK][BT];

  const int L = blockIdx.x;
  int by = (int)(96.5 - sqrt(96.5 * 96.5 - 2.0 * (double)L));
  while (by > 0 && by * NTILES - by * (by - 1) / 2 > L) --by;
  while ((by + 1) * NTILES - (by + 1) * by / 2 <= L) ++by;
  const int bx = by + (L - (by * NTILES - by * (by - 1) / 2));

  const int n0 = by * BT;
  const int m0 = bx * BT;
  const int t = threadIdx.x;
  const int tx = t & 15, ty = t >> 4;
  const int sr = t >> 1;
  const int sk = (t & 1) * 16;

  float acc[8][8] = {};

  for (int k0 = 0; k0 < D_FEAT; k0 += BK) {
    __syncthreads();
    {
      const float ia = nrm[n0 + sr];
      const float ib = nrm[m0 + sr];
      #pragma unroll
      for (int q = 0; q < 4; ++q) {
        const int c = sk + q * 4;
        const float4 xa = *reinterpret_cast<const float4*>(
            &x[(size_t)(n0 + sr) * D_FEAT + k0 + c]);
        const float4 xb = *reinterpret_cast<const float4*>(
            &x[(size_t)(m0 + sr) * D_FEAT + k0 + c]);
        const float4 wa = *reinterpret_cast<const float4*>(&w0[k0 + c]);
        const float4 wb = *reinterpret_cast<const float4*>(&w1[k0 + c]);
        const float xaf[4] = {xa.x, xa.y, xa.z, xa.w};
        const float xbf[4] = {xb.x, xb.y, xb.z, xb.w};
        const float w0f[4] = {wa.x, wa.y, wa.z, wa.w};
        const float w1f[4] = {wb.x, wb.y, wb.z, wb.w};
        #pragma unroll
        for (int e = 0; e < 4; ++e) {
          As[c + e][sr] = __fdiv_rn(np_g(xaf[e], w0f[e], w1f[e]), ia);
          Bs[c + e][sr] = __fdiv_rn(np_g(xbf[e], w0f[e], w1f[e]), ib);
        }
      }
    }
    __syncthreads();

    for (int kk = 0; kk < BK; ++kk) {
      const float4 a0 = *reinterpret_cast<const float4*>(&As[kk][ty * 4]);
      const float4 a1 = *reinterpret_cast<const float4*>(&As[kk][64 + ty * 4]);
      const float4 b0 = *reinterpret_cast<const float4*>(&Bs[kk][tx * 4]);
      const float4 b1 = *reinterpret_cast<const float4*>(&Bs[kk][64 + tx * 4]);
      const float af[8] = {a0.x, a0.y, a0.z, a0.w, a1.x, a1.y, a1.z, a1.w};
      const float bf[8] = {b0.x, b0.y, b0.z, b0.w, b1.x, b1.y, b1.z, b1.w};
      #pragma unroll
      for (int i = 0; i < 8; ++i)
        #pragma unroll
        for (int j = 0; j < 8; ++j)
          acc[i][j] = __builtin_fmaf(af[i], bf[j], acc[i][j]);
    }
  }

  #pragma unroll
  for (int i = 0; i < 8; ++i) {
    const int row = n0 + (i >> 2) * 64 + ty * 4 + (i & 3);
    float4 o0, o1;
    o0.x = acc[i][0]; o0.y = acc[i][1]; o0.z = acc[i][2]; o0.w = acc[i][3];
    o1.x = acc[i][4]; o1.y = acc[i][5]; o1.z = acc[i][6]; o1.w = acc[i][7];
    *reinterpret_cast<float4*>(&out[(size_t)row * N_NODES + m0 + tx * 4]) = o0;
    *reinterpret_cast<float4*>(&out[(size_t)row * N_NODES + m0 + 64 + tx * 4]) = o1;
  }

  if (bx != by) {
    #pragma unroll
    for (int j = 0; j < 8; ++j) {
      const int mrow = m0 + (j >> 2) * 64 + tx * 4 + (j & 3);
      float4 o0, o1;
      o0.x = acc[0][j]; o0.y = acc[1][j]; o0.z = acc[2][j]; o0.w = acc[3][j];
      o1.x = acc[4][j]; o1.y = acc[5][j]; o1.z = acc[6][j]; o1.w = acc[7][j];
      *reinterpret_cast<float4*>(&out[(size_t)mrow * N_NODES + n0 + ty * 4]) = o0;
      *reinterpret_cast<float4*>(&out[(size_t)mrow * N_NODES + n0 + 64 + ty * 4]) = o1;
    }
  }
}

// ---------------------------------------------------------------------------
// Kernel 3: per-row top-K mask + relu via BUCKET SELECT (exact).
// Finds T = exact K-th largest sortable-uint via histogram refinement
// (<= 3 passes), then applies the verified write phase (count >T/==T,
// lowest-index ties). Selection semantics identical to the binary search.
// ---------------------------------------------------------------------------
__device__ inline float att_decode(unsigned uu) {
  return (uu & 0x80000000u) ? __uint_as_float(uu & 0x7FFFFFFFu)
                            : __uint_as_float(~uu);
}

#define HBINS 2048

__global__ __launch_bounds__(256) void att_topk_kernel(float* __restrict__ s) {
  const int n = blockIdx.x;
  float* row = s + (size_t)n * N_NODES;
  const int t = threadIdx.x;
  const int lane = t & 63, wid = t >> 6;

  unsigned u[48];
#pragma unroll
  for (int i = 0; i < 12; ++i) {
    float4 v = reinterpret_cast<const float4*>(row)[t + 256 * i];
    const float f[4] = {v.x, v.y, v.z, v.w};
#pragma unroll
    for (int j = 0; j < 4; ++j) {
      unsigned b = __float_as_uint(f[j]);
      u[i * 4 + j] = (b & 0x80000000u) ? ~b : (b | 0x80000000u);
    }
  }

  __shared__ unsigned hist[HBINS];  // reused as candidate-value store
  __shared__ unsigned wmn[4], wmx[4];
  __shared__ int wred[4];
  __shared__ unsigned bc_mn, bc_mx, bc_T;
  __shared__ int bc_B, bc_above, bc_cnt, bc_cand;
  __shared__ int cnt_s;

  // ---- block min/max of u ----
  unsigned mymn = u[0], mymx = u[0];
#pragma unroll
  for (int i = 1; i < 48; ++i) {
    mymn = u[i] < mymn ? u[i] : mymn;
    mymx = u[i] > mymx ? u[i] : mymx;
  }
#pragma unroll
  for (int o = 32; o > 0; o >>= 1) {
    const unsigned a = __shfl_down(mymn, o);
    const unsigned b = __shfl_down(mymx, o);
    mymn = a < mymn ? a : mymn;
    mymx = b > mymx ? b : mymx;
  }
  if (lane == 0) { wmn[wid] = mymn; wmx[wid] = mymx; }
  __syncthreads();
  if (t == 0) {
    unsigned mn = wmn[0], mx = wmx[0];
    for (int w = 1; w < 4; ++w) {
      mn = wmn[w] < mn ? wmn[w] : mn;
      mx = wmx[w] > mx ? wmx[w] : mx;
    }
    bc_mn = mn; bc_mx = mx;
  }
  __syncthreads();

  unsigned T;
  if (bc_mn == bc_mx) {
    T = bc_mn;  // all equal: ties resolved by index in write phase
  } else {
    unsigned cur_lo = bc_mn;
    unsigned cur_range = bc_mx - bc_mn;  // inclusive range [cur_lo, cur_lo+cur_range]
    int above_total = 0;
    bool done = false;
    for (int pass = 0; pass < 4 && !done; ++pass) {
      const int bits = 32 - __clz(cur_range);
      const int sh = bits > 11 ? bits - 11 : 0;
      // zero histogram
#pragma unroll
      for (int q = 0; q < HBINS / 256; ++q) hist[t + 256 * q] = 0u;
      __syncthreads();
      // fill
#pragma unroll
      for (int i = 0; i < 48; ++i) {
        const unsigned rel = u[i] - cur_lo;
        if (u[i] >= cur_lo && rel <= cur_range)
          atomicAdd(&hist[rel >> sh], 1u);
      }
      __syncthreads();
      // suffix scan: thread t owns bins [8t, 8t+8)
      int hloc[8];
      int part = 0;
#pragma unroll
      for (int q = 0; q < 8; ++q) { hloc[q] = (int)hist[8 * t + q]; part += hloc[q]; }
      int v = part;
#pragma unroll
      for (int o = 1; o < 64; o <<= 1) {
        const int z = __shfl_down(v, o);
        if (lane + o < 64) v += z;
      }
      if (lane == 0) wred[wid] = v;
      __syncthreads();
      int wsuf = 0;
      for (int w = wid + 1; w < 4; ++w) wsuf += wred[w];
      const int suffix_incl = v + wsuf;  // sum of partials for threads >= t
      int run = suffix_incl - part;      // elements in bins above this thread's block
      int fB = -1, fAbove = 0, fCnt = 0;
#pragma unroll
      for (int q = 7; q >= 0; --q) {
        const int above = run;
        const int cnt = hloc[q];
        if (cnt > 0 && above_total + above < K_TOP &&
            above_total + above + cnt >= K_TOP) {
          fB = 8 * t + q; fAbove = above; fCnt = cnt;
        }
        run += cnt;
      }
      if (fB >= 0) { bc_B = fB; bc_above = fAbove; bc_cnt = fCnt; }
      __syncthreads();
      const int B = bc_B;
      const int aboveB = bc_above;
      const int cntB = bc_cnt;
      const unsigned bin_lo = cur_lo + ((unsigned)B << sh);
      if (sh == 0) {
        T = bin_lo;  // span-1 bin: all entries equal T
        done = true;
      } else if (cntB <= HBINS) {
        // collect candidate values (reuse hist storage)
        if (t == 0) bc_cand = 0;
        __syncthreads();
#pragma unroll
        for (int i = 0; i < 48; ++i) {
          const unsigned rel = u[i] - cur_lo;
          if (u[i] >= cur_lo && rel <= cur_range && (int)(rel >> sh) == B) {
            const int slot = atomicAdd(&bc_cand, 1);
            hist[slot] = u[i];
          }
        }
        __syncthreads();
        const int m = bc_cand;                       // == cntB
        const int kb = K_TOP - above_total - aboveB; // 1..cntB
        for (int e = t; e < m; e += 256) {
          const unsigned ce = hist[e];
          int gt = 0, eq = 0;
          for (int e2 = 0; e2 < m; ++e2) {
            const unsigned c2 = hist[e2];
            gt += (c2 > ce) ? 1 : 0;
            eq += (c2 == ce) ? 1 : 0;
          }
          if (gt < kb && gt + eq >= kb) bc_T = ce;  // unique value; races benign
        }
        __syncthreads();
        T = bc_T;
        done = true;
      } else {
        // narrow into bin B and re-histogram
        above_total += aboveB;
        cur_lo = bin_lo;
        cur_range = (1u << sh) - 1u;
      }
      __syncthreads();
    }
  }

  // ---- write phase (verified since r6): count >T / ==T, lowest-index ties ----
  {
    int cg = 0, ce = 0;
#pragma unroll
    for (int i = 0; i < 48; ++i) {
      cg += (u[i] > T) ? 1 : 0;
      ce += (u[i] == T) ? 1 : 0;
    }
    int packed = (cg << 16) | ce;
#pragma unroll
    for (int o = 32; o > 0; o >>= 1) packed += __shfl_down(packed, o);
    if (t == 0) cnt_s = 0;
    __syncthreads();
    if ((t & 63) == 0) atomicAdd(&cnt_s, packed);
    __syncthreads();
  }
  const int tot = cnt_s;
  __syncthreads();
  const int tot_gt = tot >> 16;
  const int tot_eq = tot & 0xFFFF;
  const int need = K_TOP - tot_gt;

  if (tot_eq == need) {
#pragma unroll
    for (int i = 0; i < 12; ++i) {
      float vals[4];
#pragma unroll
      for (int j = 0; j < 4; ++j) {
        const unsigned uu = u[i * 4 + j];
        const float f = att_decode(uu);
        vals[j] = (uu >= T) ? fmaxf(f, 0.0f) : 0.0f;
      }
      float4 o; o.x = vals[0]; o.y = vals[1]; o.z = vals[2]; o.w = vals[3];
      reinterpret_cast<float4*>(row)[t + 256 * i] = o;
    }
  } else {
    __shared__ int eqc[12][256];
#pragma unroll
    for (int i = 0; i < 12; ++i) {
      int c = 0;
#pragma unroll
      for (int j = 0; j < 4; ++j) c += (u[i * 4 + j] == T) ? 1 : 0;
      eqc[i][t] = c;
    }
    __syncthreads();
    int base[12];
    {
      int run = 0;
      for (int i = 0; i < 12; ++i) {
        int pre = 0, tt_tot = 0;
        for (int tt = 0; tt < 256; ++tt) {
          const int vv = eqc[i][tt];
          if (tt < t) pre += vv;
          tt_tot += vv;
        }
        base[i] = run + pre;
        run += tt_tot;
      }
    }
#pragma unroll
    for (int i = 0; i < 12; ++i) {
      float vals[4];
      int r = base[i];
#pragma unroll
      for (int j = 0; j < 4; ++j) {
        const unsigned uu = u[i * 4 + j];
        const float f = att_decode(uu);
        bool keep = false;
        if (uu > T) keep = true;
        else if (uu == T) { keep = (r < need); ++r; }
        vals[j] = keep ? fmaxf(f, 0.0f) : 0.0f;
      }
      float4 o; o.x = vals[0]; o.y = vals[1]; o.z = vals[2]; o.w = vals[3];
      reinterpret_cast<float4*>(row)[t + 256 * i] = o;
    }
  }
}

// ---------------------------------------------------------------------------
extern "C" void kernel_launch(void* const* d_in, const int* in_sizes, int n_in,
                              void* d_out, int out_size, void* d_ws, size_t ws_size,
                              hipStream_t stream) {
  const float* x  = (const float*)d_in[0];
  const float* w0 = (const float*)d_in[1];
  const float* w1 = (const float*)d_in[2];
  float* out = (float*)d_out;
  float* nrm = (float*)d_ws;  // 48 KiB scratch

  np_norm_kernel<<<N_NODES / 256, 256, 0, stream>>>(x, w0, w1, nrm);

  np_gemm_kernel<<<NBLOCKS, 256, 0, stream>>>(x, w0, w1, nrm, out);

  att_topk_kernel<<<N_NODES, 256, 0, stream>>>(out);
}

// Round 10
// 870.831 us; speedup vs baseline: 2.5541x; 1.0125x over previous
//
#include <hip/hip_runtime.h>
#include <cstdint>
#include <cstddef>
#include <math.h>

#define N_NODES 12288
#define D_FEAT  256
#define K_TOP   31

// np-f32 elementwise chain: g = relu(x*w0)*w1, IEEE f32 per op, no contraction.
__device__ __forceinline__ float np_g(float xv, float w0v, float w1v) {
  #pragma clang fp contract(off)
  float t = __fmul_rn(xv, w0v);
  t = fmaxf(t, 0.0f);
  return __fmul_rn(t, w1v);
}

// ---------------------------------------------------------------------------
// Kernel 1 (frozen since r6): norm[n] = max(sqrt(np.sum(h*h, -1)), 1e-12),
// replicating numpy FLOAT_pairwise_sum for n=256 (scalar 8-accumulator base).
// ---------------------------------------------------------------------------
__global__ __launch_bounds__(256) void np_norm_kernel(
    const float* __restrict__ x, const float* __restrict__ w0,
    const float* __restrict__ w1, float* __restrict__ nrm) {
  #pragma clang fp contract(off)
  const int n = blockIdx.x * blockDim.x + threadIdx.x;
  if (n >= N_NODES) return;
  const float* xr = x + (size_t)n * D_FEAT;
  float blk[2];
  #pragma unroll
  for (int b = 0; b < 2; ++b) {
    float r[8];
    #pragma unroll
    for (int j = 0; j < 8; ++j) {
      const int d = 128 * b + j;
      const float g = np_g(xr[d], w0[d], w1[d]);
      r[j] = __fmul_rn(g, g);
    }
    for (int i = 8; i < 128; i += 8) {
      #pragma unroll
      for (int j = 0; j < 8; ++j) {
        const int d = 128 * b + i + j;
        const float g = np_g(xr[d], w0[d], w1[d]);
        r[j] = __fadd_rn(r[j], __fmul_rn(g, g));
      }
    }
    blk[b] = __fadd_rn(
        __fadd_rn(__fadd_rn(r[0], r[1]), __fadd_rn(r[2], r[3])),
        __fadd_rn(__fadd_rn(r[4], r[5]), __fadd_rn(r[6], r[7])));
  }
  const float tot = __fadd_rn(blk[0], blk[1]);
  nrm[n] = fmaxf(__fsqrt_rn(tot), 1e-12f);
}

// ---------------------------------------------------------------------------
// Kernel 2: symmetric-half BLAS-chain GEMM (arithmetic frozen since r6):
//   acc = 0; for d = 0..255 ascending: acc = fmaf(h_n[d], h_m[d], acc)
// r10 change: mirror tiles go through an LDS transpose so that mirror
// stores are full-128B-line (fixes partial-line RMW: FETCH_SIZE ~556 MB).
// LDS: As/Bs (32 KB, dead after k-loop) unioned with tb[64][132] (33.8 KB).
// ---------------------------------------------------------------------------
#define BT 128
#define BK 32
#define TBW 132
#define NTILES (N_NODES / BT)                // 96
#define NBLOCKS (NTILES * (NTILES + 1) / 2)  // 4656

__global__ __launch_bounds__(256, 4) void np_gemm_kernel(
    const float* __restrict__ x, const float* __restrict__ w0,
    const float* __restrict__ w1, const float* __restrict__ nrm,
    float* __restrict__ out) {
  #pragma clang fp contract(off)
  __shared__ __align__(16) float smem[64 * TBW];  // 8448 floats >= 2*BK*BT
  float (*As)[BT] = reinterpret_cast<float (*)[BT]>(smem);
  float (*Bs)[BT] = reinterpret_cast<float (*)[BT]>(smem + BK * BT);
  float (*tb)[TBW] = reinterpret_cast<float (*)[TBW]>(smem);

  const int L = blockIdx.x;
  int by = (int)(96.5 - sqrt(96.5 * 96.5 - 2.0 * (double)L));
  while (by > 0 && by * NTILES - by * (by - 1) / 2 > L) --by;
  while ((by + 1) * NTILES - (by + 1) * by / 2 <= L) ++by;
  const int bx = by + (L - (by * NTILES - by * (by - 1) / 2));

  const int n0 = by * BT;
  const int m0 = bx * BT;
  const int t = threadIdx.x;
  const int tx = t & 15, ty = t >> 4;
  const int sr = t >> 1;
  const int sk = (t & 1) * 16;

  float acc[8][8] = {};

  for (int k0 = 0; k0 < D_FEAT; k0 += BK) {
    __syncthreads();
    {
      const float ia = nrm[n0 + sr];
      const float ib = nrm[m0 + sr];
      #pragma unroll
      for (int q = 0; q < 4; ++q) {
        const int c = sk + q * 4;
        const float4 xa = *reinterpret_cast<const float4*>(
            &x[(size_t)(n0 + sr) * D_FEAT + k0 + c]);
        const float4 xb = *reinterpret_cast<const float4*>(
            &x[(size_t)(m0 + sr) * D_FEAT + k0 + c]);
        const float4 wa = *reinterpret_cast<const float4*>(&w0[k0 + c]);
        const float4 wb = *reinterpret_cast<const float4*>(&w1[k0 + c]);
        const float xaf[4] = {xa.x, xa.y, xa.z, xa.w};
        const float xbf[4] = {xb.x, xb.y, xb.z, xb.w};
        const float w0f[4] = {wa.x, wa.y, wa.z, wa.w};
        const float w1f[4] = {wb.x, wb.y, wb.z, wb.w};
        #pragma unroll
        for (int e = 0; e < 4; ++e) {
          As[c + e][sr] = __fdiv_rn(np_g(xaf[e], w0f[e], w1f[e]), ia);
          Bs[c + e][sr] = __fdiv_rn(np_g(xbf[e], w0f[e], w1f[e]), ib);
        }
      }
    }
    __syncthreads();

    for (int kk = 0; kk < BK; ++kk) {
      const float4 a0 = *reinterpret_cast<const float4*>(&As[kk][ty * 4]);
      const float4 a1 = *reinterpret_cast<const float4*>(&As[kk][64 + ty * 4]);
      const float4 b0 = *reinterpret_cast<const float4*>(&Bs[kk][tx * 4]);
      const float4 b1 = *reinterpret_cast<const float4*>(&Bs[kk][64 + tx * 4]);
      const float af[8] = {a0.x, a0.y, a0.z, a0.w, a1.x, a1.y, a1.z, a1.w};
      const float bf[8] = {b0.x, b0.y, b0.z, b0.w, b1.x, b1.y, b1.z, b1.w};
      #pragma unroll
      for (int i = 0; i < 8; ++i)
        #pragma unroll
        for (int j = 0; j < 8; ++j)
          acc[i][j] = __builtin_fmaf(af[i], bf[j], acc[i][j]);
    }
  }

  // Direct tile store: s[n][m] — full-line wave stores (unchanged).
  #pragma unroll
  for (int i = 0; i < 8; ++i) {
    const int row = n0 + (i >> 2) * 64 + ty * 4 + (i & 3);
    float4 o0, o1;
    o0.x = acc[i][0]; o0.y = acc[i][1]; o0.z = acc[i][2]; o0.w = acc[i][3];
    o1.x = acc[i][4]; o1.y = acc[i][5]; o1.z = acc[i][6]; o1.w = acc[i][7];
    *reinterpret_cast<float4*>(&out[(size_t)row * N_NODES + m0 + tx * 4]) = o0;
    *reinterpret_cast<float4*>(&out[(size_t)row * N_NODES + m0 + 64 + tx * 4]) = o1;
  }

  // Mirror tile store via LDS transpose: full-128B-line writes.
  // Logical: out[m0+ml][n0+nl] = acc value at (nlocal=nl, mlocal=ml).
  if (bx != by) {
    #pragma unroll
    for (int hh = 0; hh < 2; ++hh) {  // mirror-row halves 0..63, 64..127
      __syncthreads();  // As/Bs (or prev half) reads done before overwrite
      #pragma unroll
      for (int r = 0; r < 4; ++r) {
        const int j = hh * 4 + r;
        const int ml = tx * 4 + r;  // mirror row local to this half
        #pragma unroll
        for (int ih = 0; ih < 2; ++ih) {
          float4 v;
          v.x = acc[ih * 4 + 0][j];
          v.y = acc[ih * 4 + 1][j];
          v.z = acc[ih * 4 + 2][j];
          v.w = acc[ih * 4 + 3][j];
          *reinterpret_cast<float4*>(&tb[ml][ih * 64 + ty * 4]) = v;
        }
      }
      __syncthreads();
      #pragma unroll
      for (int p = 0; p < 8; ++p) {
        const int row = (t >> 5) + 8 * p;   // 2 rows per wave
        const int col = (t & 31) * 4;       // 32 lanes x 16B = full row (512B)
        const float4 v = *reinterpret_cast<const float4*>(&tb[row][col]);
        *reinterpret_cast<float4*>(
            &out[(size_t)(m0 + hh * 64 + row) * N_NODES + n0 + col]) = v;
      }
    }
  }
}

// ---------------------------------------------------------------------------
// Kernel 3 (frozen since r9): per-row top-K mask + relu via exact bucket
// select; write phase counts >T/==T with lowest-index ties.
// ---------------------------------------------------------------------------
__device__ inline float att_decode(unsigned uu) {
  return (uu & 0x80000000u) ? __uint_as_float(uu & 0x7FFFFFFFu)
                            : __uint_as_float(~uu);
}

#define HBINS 2048

__global__ __launch_bounds__(256) void att_topk_kernel(float* __restrict__ s) {
  const int n = blockIdx.x;
  float* row = s + (size_t)n * N_NODES;
  const int t = threadIdx.x;
  const int lane = t & 63, wid = t >> 6;

  unsigned u[48];
#pragma unroll
  for (int i = 0; i < 12; ++i) {
    float4 v = reinterpret_cast<const float4*>(row)[t + 256 * i];
    const float f[4] = {v.x, v.y, v.z, v.w};
#pragma unroll
    for (int j = 0; j < 4; ++j) {
      unsigned b = __float_as_uint(f[j]);
      u[i * 4 + j] = (b & 0x80000000u) ? ~b : (b | 0x80000000u);
    }
  }

  __shared__ unsigned hist[HBINS];
  __shared__ unsigned wmn[4], wmx[4];
  __shared__ int wred[4];
  __shared__ unsigned bc_mn, bc_mx, bc_T;
  __shared__ int bc_B, bc_above, bc_cnt, bc_cand;
  __shared__ int cnt_s;

  unsigned mymn = u[0], mymx = u[0];
#pragma unroll
  for (int i = 1; i < 48; ++i) {
    mymn = u[i] < mymn ? u[i] : mymn;
    mymx = u[i] > mymx ? u[i] : mymx;
  }
#pragma unroll
  for (int o = 32; o > 0; o >>= 1) {
    const unsigned a = __shfl_down(mymn, o);
    const unsigned b = __shfl_down(mymx, o);
    mymn = a < mymn ? a : mymn;
    mymx = b > mymx ? b : mymx;
  }
  if (lane == 0) { wmn[wid] = mymn; wmx[wid] = mymx; }
  __syncthreads();
  if (t == 0) {
    unsigned mn = wmn[0], mx = wmx[0];
    for (int w = 1; w < 4; ++w) {
      mn = wmn[w] < mn ? wmn[w] : mn;
      mx = wmx[w] > mx ? wmx[w] : mx;
    }
    bc_mn = mn; bc_mx = mx;
  }
  __syncthreads();

  unsigned T;
  if (bc_mn == bc_mx) {
    T = bc_mn;
  } else {
    unsigned cur_lo = bc_mn;
    unsigned cur_range = bc_mx - bc_mn;
    int above_total = 0;
    bool done = false;
    for (int pass = 0; pass < 4 && !done; ++pass) {
      const int bits = 32 - __clz(cur_range);
      const int sh = bits > 11 ? bits - 11 : 0;
#pragma unroll
      for (int q = 0; q < HBINS / 256; ++q) hist[t + 256 * q] = 0u;
      __syncthreads();
#pragma unroll
      for (int i = 0; i < 48; ++i) {
        const unsigned rel = u[i] - cur_lo;
        if (u[i] >= cur_lo && rel <= cur_range)
          atomicAdd(&hist[rel >> sh], 1u);
      }
      __syncthreads();
      int hloc[8];
      int part = 0;
#pragma unroll
      for (int q = 0; q < 8; ++q) { hloc[q] = (int)hist[8 * t + q]; part += hloc[q]; }
      int v = part;
#pragma unroll
      for (int o = 1; o < 64; o <<= 1) {
        const int z = __shfl_down(v, o);
        if (lane + o < 64) v += z;
      }
      if (lane == 0) wred[wid] = v;
      __syncthreads();
      int wsuf = 0;
      for (int w = wid + 1; w < 4; ++w) wsuf += wred[w];
      const int suffix_incl = v + wsuf;
      int run = suffix_incl - part;
      int fB = -1, fAbove = 0, fCnt = 0;
#pragma unroll
      for (int q = 7; q >= 0; --q) {
        const int above = run;
        const int cnt = hloc[q];
        if (cnt > 0 && above_total + above < K_TOP &&
            above_total + above + cnt >= K_TOP) {
          fB = 8 * t + q; fAbove = above; fCnt = cnt;
        }
        run += cnt;
      }
      if (fB >= 0) { bc_B = fB; bc_above = fAbove; bc_cnt = fCnt; }
      __syncthreads();
      const int B = bc_B;
      const int aboveB = bc_above;
      const int cntB = bc_cnt;
      const unsigned bin_lo = cur_lo + ((unsigned)B << sh);
      if (sh == 0) {
        T = bin_lo;
        done = true;
      } else if (cntB <= HBINS) {
        if (t == 0) bc_cand = 0;
        __syncthreads();
#pragma unroll
        for (int i = 0; i < 48; ++i) {
          const unsigned rel = u[i] - cur_lo;
          if (u[i] >= cur_lo && rel <= cur_range && (int)(rel >> sh) == B) {
            const int slot = atomicAdd(&bc_cand, 1);
            hist[slot] = u[i];
          }
        }
        __syncthreads();
        const int m = bc_cand;
        const int kb = K_TOP - above_total - aboveB;
        for (int e = t; e < m; e += 256) {
          const unsigned ce = hist[e];
          int gt = 0, eq = 0;
          for (int e2 = 0; e2 < m; ++e2) {
            const unsigned c2 = hist[e2];
            gt += (c2 > ce) ? 1 : 0;
            eq += (c2 == ce) ? 1 : 0;
          }
          if (gt < kb && gt + eq >= kb) bc_T = ce;
        }
        __syncthreads();
        T = bc_T;
        done = true;
      } else {
        above_total += aboveB;
        cur_lo = bin_lo;
        cur_range = (1u << sh) - 1u;
      }
      __syncthreads();
    }
  }

  {
    int cg = 0, ce = 0;
#pragma unroll
    for (int i = 0; i < 48; ++i) {
      cg += (u[i] > T) ? 1 : 0;
      ce += (u[i] == T) ? 1 : 0;
    }
    int packed = (cg << 16) | ce;
#pragma unroll
    for (int o = 32; o > 0; o >>= 1) packed += __shfl_down(packed, o);
    if (t == 0) cnt_s = 0;
    __syncthreads();
    if ((t & 63) == 0) atomicAdd(&cnt_s, packed);
    __syncthreads();
  }
  const int tot = cnt_s;
  __syncthreads();
  const int tot_gt = tot >> 16;
  const int tot_eq = tot & 0xFFFF;
  const int need = K_TOP - tot_gt;

  if (tot_eq == need) {
#pragma unroll
    for (int i = 0; i < 12; ++i) {
      float vals[4];
#pragma unroll
      for (int j = 0; j < 4; ++j) {
        const unsigned uu = u[i * 4 + j];
        const float f = att_decode(uu);
        vals[j] = (uu >= T) ? fmaxf(f, 0.0f) : 0.0f;
      }
      float4 o; o.x = vals[0]; o.y = vals[1]; o.z = vals[2]; o.w = vals[3];
      reinterpret_cast<float4*>(row)[t + 256 * i] = o;
    }
  } else {
    __shared__ int eqc[12][256];
#pragma unroll
    for (int i = 0; i < 12; ++i) {
      int c = 0;
#pragma unroll
      for (int j = 0; j < 4; ++j) c += (u[i * 4 + j] == T) ? 1 : 0;
      eqc[i][t] = c;
    }
    __syncthreads();
    int base[12];
    {
      int run = 0;
      for (int i = 0; i < 12; ++i) {
        int pre = 0, tt_tot = 0;
        for (int tt = 0; tt < 256; ++tt) {
          const int vv = eqc[i][tt];
          if (tt < t) pre += vv;
          tt_tot += vv;
        }
        base[i] = run + pre;
        run += tt_tot;
      }
    }
#pragma unroll
    for (int i = 0; i < 12; ++i) {
      float vals[4];
      int r = base[i];
#pragma unroll
      for (int j = 0; j < 4; ++j) {
        const unsigned uu = u[i * 4 + j];
        const float f = att_decode(uu);
        bool keep = false;
        if (uu > T) keep = true;
        else if (uu == T) { keep = (r < need); ++r; }
        vals[j] = keep ? fmaxf(f, 0.0f) : 0.0f;
      }
      float4 o; o.x = vals[0]; o.y = vals[1]; o.z = vals[2]; o.w = vals[3];
      reinterpret_cast<float4*>(row)[t + 256 * i] = o;
    }
  }
}

// ---------------------------------------------------------------------------
extern "C" void kernel_launch(void* const* d_in, const int* in_sizes, int n_in,
                              void* d_out, int out_size, void* d_ws, size_t ws_size,
                              hipStream_t stream) {
  const float* x  = (const float*)d_in[0];
  const float* w0 = (const float*)d_in[1];
  const float* w1 = (const float*)d_in[2];
  float* out = (float*)d_out;
  float* nrm = (float*)d_ws;  // 48 KiB scratch

  np_norm_kernel<<<N_NODES / 256, 256, 0, stream>>>(x, w0, w1, nrm);

  np_gemm_kernel<<<NBLOCKS, 256, 0, stream>>>(x, w0, w1, nrm, out);

  att_topk_kernel<<<N_NODES, 256, 0, stream>>>(out);
}

// Round 12
// 701.626 us; speedup vs baseline: 3.1700x; 1.2412x over previous
//
#include <hip/hip_runtime.h>
#include <cstdint>
#include <cstddef>
#include <math.h>

#define N_NODES 12288
#define D_FEAT  256
#define K_TOP   31

typedef float nfloat4 __attribute__((ext_vector_type(4)));

// np-f32 elementwise chain: g = relu(x*w0)*w1, IEEE f32 per op, no contraction.
__device__ __forceinline__ float np_g(float xv, float w0v, float w1v) {
  #pragma clang fp contract(off)
  float t = __fmul_rn(xv, w0v);
  t = fmaxf(t, 0.0f);
  return __fmul_rn(t, w1v);
}

__device__ __forceinline__ void nt_store4(float* p, float4 v) {
  nfloat4 nv;
  nv.x = v.x; nv.y = v.y; nv.z = v.z; nv.w = v.w;
  __builtin_nontemporal_store(nv, reinterpret_cast<nfloat4*>(p));
}

// ---------------------------------------------------------------------------
// Kernel 1 (frozen since r6): norm[n] = max(sqrt(np.sum(h*h, -1)), 1e-12),
// replicating numpy FLOAT_pairwise_sum for n=256 (scalar 8-accumulator base).
// ---------------------------------------------------------------------------
__global__ __launch_bounds__(256) void np_norm_kernel(
    const float* __restrict__ x, const float* __restrict__ w0,
    const float* __restrict__ w1, float* __restrict__ nrm) {
  #pragma clang fp contract(off)
  const int n = blockIdx.x * blockDim.x + threadIdx.x;
  if (n >= N_NODES) return;
  const float* xr = x + (size_t)n * D_FEAT;
  float blk[2];
  #pragma unroll
  for (int b = 0; b < 2; ++b) {
    float r[8];
    #pragma unroll
    for (int j = 0; j < 8; ++j) {
      const int d = 128 * b + j;
      const float g = np_g(xr[d], w0[d], w1[d]);
      r[j] = __fmul_rn(g, g);
    }
    for (int i = 8; i < 128; i += 8) {
      #pragma unroll
      for (int j = 0; j < 8; ++j) {
        const int d = 128 * b + i + j;
        const float g = np_g(xr[d], w0[d], w1[d]);
        r[j] = __fadd_rn(r[j], __fmul_rn(g, g));
      }
    }
    blk[b] = __fadd_rn(
        __fadd_rn(__fadd_rn(r[0], r[1]), __fadd_rn(r[2], r[3])),
        __fadd_rn(__fadd_rn(r[4], r[5]), __fadd_rn(r[6], r[7])));
  }
  const float tot = __fadd_rn(blk[0], blk[1]);
  nrm[n] = fmaxf(__fsqrt_rn(tot), 1e-12f);
}

// ---------------------------------------------------------------------------
// Kernel 1b: h[n][d] = g(n,d) / nrm[n] — precomputed ONCE (element chain
// identical to the inline staging it replaces). One float4 per thread.
// ---------------------------------------------------------------------------
__global__ __launch_bounds__(256) void np_h_kernel(
    const float* __restrict__ x, const float* __restrict__ w0,
    const float* __restrict__ w1, const float* __restrict__ nrm,
    float* __restrict__ h) {
  #pragma clang fp contract(off)
  const int q = blockIdx.x * blockDim.x + threadIdx.x;  // float4 index
  const int base = q * 4;
  if (base >= N_NODES * D_FEAT) return;
  const int n = base >> 8;
  const int d = base & (D_FEAT - 1);
  const float ia = nrm[n];
  const float4 xv = *reinterpret_cast<const float4*>(&x[base]);
  const float4 w0v = *reinterpret_cast<const float4*>(&w0[d]);
  const float4 w1v = *reinterpret_cast<const float4*>(&w1[d]);
  float4 o;
  o.x = __fdiv_rn(np_g(xv.x, w0v.x, w1v.x), ia);
  o.y = __fdiv_rn(np_g(xv.y, w0v.y, w1v.y), ia);
  o.z = __fdiv_rn(np_g(xv.z, w0v.z, w1v.z), ia);
  o.w = __fdiv_rn(np_g(xv.w, w0v.w, w1v.w), ia);
  *reinterpret_cast<float4*>(&h[base]) = o;
}

// ---------------------------------------------------------------------------
// Kernel 2: symmetric-half BLAS-chain GEMM (arithmetic frozen since r6):
//   acc = 0; for d = 0..255 ascending: acc = fmaf(h_n[d], h_m[d], acc)
// r11/r12: __launch_bounds__(256,2) so acc[8][8] lives in architectural
// VGPRs (r10's (256,4) cap pushed it to AGPRs -> accvgpr mov overhead);
// staging from precomputed h (PRE=1) removes redundant np_g/div chains;
// non-temporal output stores kill L2 write-allocate FETCH.
// ---------------------------------------------------------------------------
#define BT 128
#define BK 32
#define TBW 132
#define NTILES (N_NODES / BT)                // 96
#define NBLOCKS (NTILES * (NTILES + 1) / 2)  // 4656

template <int PRE>
__global__ __launch_bounds__(256, 2) void np_gemm_kernel(
    const float* __restrict__ x, const float* __restrict__ w0,
    const float* __restrict__ w1, const float* __restrict__ nrm,
    const float* __restrict__ h, float* __restrict__ out) {
  #pragma clang fp contract(off)
  __shared__ __align__(16) float smem[64 * TBW];  // 8448 floats >= 2*BK*BT
  float (*As)[BT] = reinterpret_cast<float (*)[BT]>(smem);
  float (*Bs)[BT] = reinterpret_cast<float (*)[BT]>(smem + BK * BT);
  float (*tb)[TBW] = reinterpret_cast<float (*)[TBW]>(smem);

  const int L = blockIdx.x;
  int by = (int)(96.5 - sqrt(96.5 * 96.5 - 2.0 * (double)L));
  while (by > 0 && by * NTILES - by * (by - 1) / 2 > L) --by;
  while ((by + 1) * NTILES - (by + 1) * by / 2 <= L) ++by;
  const int bx = by + (L - (by * NTILES - by * (by - 1) / 2));

  const int n0 = by * BT;
  const int m0 = bx * BT;
  const int t = threadIdx.x;
  const int tx = t & 15, ty = t >> 4;
  const int sr = t >> 1;
  const int sk = (t & 1) * 16;

  float acc[8][8] = {};

  for (int k0 = 0; k0 < D_FEAT; k0 += BK) {
    __syncthreads();
    if (PRE) {
      #pragma unroll
      for (int q = 0; q < 4; ++q) {
        const int c = sk + q * 4;
        const float4 ha = *reinterpret_cast<const float4*>(
            &h[(size_t)(n0 + sr) * D_FEAT + k0 + c]);
        const float4 hb = *reinterpret_cast<const float4*>(
            &h[(size_t)(m0 + sr) * D_FEAT + k0 + c]);
        As[c + 0][sr] = ha.x; As[c + 1][sr] = ha.y;
        As[c + 2][sr] = ha.z; As[c + 3][sr] = ha.w;
        Bs[c + 0][sr] = hb.x; Bs[c + 1][sr] = hb.y;
        Bs[c + 2][sr] = hb.z; Bs[c + 3][sr] = hb.w;
      }
    } else {
      const float ia = nrm[n0 + sr];
      const float ib = nrm[m0 + sr];
      #pragma unroll
      for (int q = 0; q < 4; ++q) {
        const int c = sk + q * 4;
        const float4 xa = *reinterpret_cast<const float4*>(
            &x[(size_t)(n0 + sr) * D_FEAT + k0 + c]);
        const float4 xb = *reinterpret_cast<const float4*>(
            &x[(size_t)(m0 + sr) * D_FEAT + k0 + c]);
        const float4 wa = *reinterpret_cast<const float4*>(&w0[k0 + c]);
        const float4 wb = *reinterpret_cast<const float4*>(&w1[k0 + c]);
        const float xaf[4] = {xa.x, xa.y, xa.z, xa.w};
        const float xbf[4] = {xb.x, xb.y, xb.z, xb.w};
        const float w0f[4] = {wa.x, wa.y, wa.z, wa.w};
        const float w1f[4] = {wb.x, wb.y, wb.z, wb.w};
        #pragma unroll
        for (int e = 0; e < 4; ++e) {
          As[c + e][sr] = __fdiv_rn(np_g(xaf[e], w0f[e], w1f[e]), ia);
          Bs[c + e][sr] = __fdiv_rn(np_g(xbf[e], w0f[e], w1f[e]), ib);
        }
      }
    }
    __syncthreads();

    for (int kk = 0; kk < BK; ++kk) {
      const float4 a0 = *reinterpret_cast<const float4*>(&As[kk][ty * 4]);
      const float4 a1 = *reinterpret_cast<const float4*>(&As[kk][64 + ty * 4]);
      const float4 b0 = *reinterpret_cast<const float4*>(&Bs[kk][tx * 4]);
      const float4 b1 = *reinterpret_cast<const float4*>(&Bs[kk][64 + tx * 4]);
      const float af[8] = {a0.x, a0.y, a0.z, a0.w, a1.x, a1.y, a1.z, a1.w};
      const float bf[8] = {b0.x, b0.y, b0.z, b0.w, b1.x, b1.y, b1.z, b1.w};
      #pragma unroll
      for (int i = 0; i < 8; ++i)
        #pragma unroll
        for (int j = 0; j < 8; ++j)
          acc[i][j] = __builtin_fmaf(af[i], bf[j], acc[i][j]);
    }
  }

  // Direct tile store: s[n][m] — full-line nontemporal wave stores.
  #pragma unroll
  for (int i = 0; i < 8; ++i) {
    const int row = n0 + (i >> 2) * 64 + ty * 4 + (i & 3);
    float4 o0, o1;
    o0.x = acc[i][0]; o0.y = acc[i][1]; o0.z = acc[i][2]; o0.w = acc[i][3];
    o1.x = acc[i][4]; o1.y = acc[i][5]; o1.z = acc[i][6]; o1.w = acc[i][7];
    nt_store4(&out[(size_t)row * N_NODES + m0 + tx * 4], o0);
    nt_store4(&out[(size_t)row * N_NODES + m0 + 64 + tx * 4], o1);
  }

  // Mirror tile store via LDS transpose: full-128B-line nontemporal writes.
  if (bx != by) {
    #pragma unroll
    for (int hh = 0; hh < 2; ++hh) {
      __syncthreads();
      #pragma unroll
      for (int r = 0; r < 4; ++r) {
        const int j = hh * 4 + r;
        const int ml = tx * 4 + r;
        #pragma unroll
        for (int ih = 0; ih < 2; ++ih) {
          float4 v;
          v.x = acc[ih * 4 + 0][j];
          v.y = acc[ih * 4 + 1][j];
          v.z = acc[ih * 4 + 2][j];
          v.w = acc[ih * 4 + 3][j];
          *reinterpret_cast<float4*>(&tb[ml][ih * 64 + ty * 4]) = v;
        }
      }
      __syncthreads();
      #pragma unroll
      for (int p = 0; p < 8; ++p) {
        const int row = (t >> 5) + 8 * p;
        const int col = (t & 31) * 4;
        const float4 v = *reinterpret_cast<const float4*>(&tb[row][col]);
        nt_store4(&out[(size_t)(m0 + hh * 64 + row) * N_NODES + n0 + col], v);
      }
    }
  }
}

// ---------------------------------------------------------------------------
// Kernel 3 (frozen since r9): per-row top-K mask + relu via exact bucket
// select; write phase counts >T/==T with lowest-index ties.
// ---------------------------------------------------------------------------
__device__ inline float att_decode(unsigned uu) {
  return (uu & 0x80000000u) ? __uint_as_float(uu & 0x7FFFFFFFu)
                            : __uint_as_float(~uu);
}

#define HBINS 2048

__global__ __launch_bounds__(256) void att_topk_kernel(float* __restrict__ s) {
  const int n = blockIdx.x;
  float* row = s + (size_t)n * N_NODES;
  const int t = threadIdx.x;
  const int lane = t & 63, wid = t >> 6;

  unsigned u[48];
#pragma unroll
  for (int i = 0; i < 12; ++i) {
    float4 v = reinterpret_cast<const float4*>(row)[t + 256 * i];
    const float f[4] = {v.x, v.y, v.z, v.w};
#pragma unroll
    for (int j = 0; j < 4; ++j) {
      unsigned b = __float_as_uint(f[j]);
      u[i * 4 + j] = (b & 0x80000000u) ? ~b : (b | 0x80000000u);
    }
  }

  __shared__ unsigned hist[HBINS];
  __shared__ unsigned wmn[4], wmx[4];
  __shared__ int wred[4];
  __shared__ unsigned bc_mn, bc_mx, bc_T;
  __shared__ int bc_B, bc_above, bc_cnt, bc_cand;
  __shared__ int cnt_s;

  unsigned mymn = u[0], mymx = u[0];
#pragma unroll
  for (int i = 1; i < 48; ++i) {
    mymn = u[i] < mymn ? u[i] : mymn;
    mymx = u[i] > mymx ? u[i] : mymx;
  }
#pragma unroll
  for (int o = 32; o > 0; o >>= 1) {
    const unsigned a = __shfl_down(mymn, o);
    const unsigned b = __shfl_down(mymx, o);
    mymn = a < mymn ? a : mymn;
    mymx = b > mymx ? b : mymx;
  }
  if (lane == 0) { wmn[wid] = mymn; wmx[wid] = mymx; }
  __syncthreads();
  if (t == 0) {
    unsigned mn = wmn[0], mx = wmx[0];
    for (int w = 1; w < 4; ++w) {
      mn = wmn[w] < mn ? wmn[w] : mn;
      mx = wmx[w] > mx ? wmx[w] : mx;
    }
    bc_mn = mn; bc_mx = mx;
  }
  __syncthreads();

  unsigned T;
  if (bc_mn == bc_mx) {
    T = bc_mn;
  } else {
    unsigned cur_lo = bc_mn;
    unsigned cur_range = bc_mx - bc_mn;
    int above_total = 0;
    bool done = false;
    for (int pass = 0; pass < 4 && !done; ++pass) {
      const int bits = 32 - __clz(cur_range);
      const int sh = bits > 11 ? bits - 11 : 0;
#pragma unroll
      for (int q = 0; q < HBINS / 256; ++q) hist[t + 256 * q] = 0u;
      __syncthreads();
#pragma unroll
      for (int i = 0; i < 48; ++i) {
        const unsigned rel = u[i] - cur_lo;
        if (u[i] >= cur_lo && rel <= cur_range)
          atomicAdd(&hist[rel >> sh], 1u);
      }
      __syncthreads();
      int hloc[8];
      int part = 0;
#pragma unroll
      for (int q = 0; q < 8; ++q) { hloc[q] = (int)hist[8 * t + q]; part += hloc[q]; }
      int v = part;
#pragma unroll
      for (int o = 1; o < 64; o <<= 1) {
        const int z = __shfl_down(v, o);
        if (lane + o < 64) v += z;
      }
      if (lane == 0) wred[wid] = v;
      __syncthreads();
      int wsuf = 0;
      for (int w = wid + 1; w < 4; ++w) wsuf += wred[w];
      const int suffix_incl = v + wsuf;
      int run = suffix_incl - part;
      int fB = -1, fAbove = 0, fCnt = 0;
#pragma unroll
      for (int q = 7; q >= 0; --q) {
        const int above = run;
        const int cnt = hloc[q];
        if (cnt > 0 && above_total + above < K_TOP &&
            above_total + above + cnt >= K_TOP) {
          fB = 8 * t + q; fAbove = above; fCnt = cnt;
        }
        run += cnt;
      }
      if (fB >= 0) { bc_B = fB; bc_above = fAbove; bc_cnt = fCnt; }
      __syncthreads();
      const int B = bc_B;
      const int aboveB = bc_above;
      const int cntB = bc_cnt;
      const unsigned bin_lo = cur_lo + ((unsigned)B << sh);
      if (sh == 0) {
        T = bin_lo;
        done = true;
      } else if (cntB <= HBINS) {
        if (t == 0) bc_cand = 0;
        __syncthreads();
#pragma unroll
        for (int i = 0; i < 48; ++i) {
          const unsigned rel = u[i] - cur_lo;
          if (u[i] >= cur_lo && rel <= cur_range && (int)(rel >> sh) == B) {
            const int slot = atomicAdd(&bc_cand, 1);
            hist[slot] = u[i];
          }
        }
        __syncthreads();
        const int m = bc_cand;
        const int kb = K_TOP - above_total - aboveB;
        for (int e = t; e < m; e += 256) {
          const unsigned ce = hist[e];
          int gt = 0, eq = 0;
          for (int e2 = 0; e2 < m; ++e2) {
            const unsigned c2 = hist[e2];
            gt += (c2 > ce) ? 1 : 0;
            eq += (c2 == ce) ? 1 : 0;
          }
          if (gt < kb && gt + eq >= kb) bc_T = ce;
        }
        __syncthreads();
        T = bc_T;
        done = true;
      } else {
        above_total += aboveB;
        cur_lo = bin_lo;
        cur_range = (1u << sh) - 1u;
      }
      __syncthreads();
    }
  }

  {
    int cg = 0, ce = 0;
#pragma unroll
    for (int i = 0; i < 48; ++i) {
      cg += (u[i] > T) ? 1 : 0;
      ce += (u[i] == T) ? 1 : 0;
    }
    int packed = (cg << 16) | ce;
#pragma unroll
    for (int o = 32; o > 0; o >>= 1) packed += __shfl_down(packed, o);
    if (t == 0) cnt_s = 0;
    __syncthreads();
    if ((t & 63) == 0) atomicAdd(&cnt_s, packed);
    __syncthreads();
  }
  const int tot = cnt_s;
  __syncthreads();
  const int tot_gt = tot >> 16;
  const int tot_eq = tot & 0xFFFF;
  const int need = K_TOP - tot_gt;

  if (tot_eq == need) {
#pragma unroll
    for (int i = 0; i < 12; ++i) {
      float vals[4];
#pragma unroll
      for (int j = 0; j < 4; ++j) {
        const unsigned uu = u[i * 4 + j];
        const float f = att_decode(uu);
        vals[j] = (uu >= T) ? fmaxf(f, 0.0f) : 0.0f;
      }
      float4 o; o.x = vals[0]; o.y = vals[1]; o.z = vals[2]; o.w = vals[3];
      reinterpret_cast<float4*>(row)[t + 256 * i] = o;
    }
  } else {
    __shared__ int eqc[12][256];
#pragma unroll
    for (int i = 0; i < 12; ++i) {
      int c = 0;
#pragma unroll
      for (int j = 0; j < 4; ++j) c += (u[i * 4 + j] == T) ? 1 : 0;
      eqc[i][t] = c;
    }
    __syncthreads();
    int base[12];
    {
      int run = 0;
      for (int i = 0; i < 12; ++i) {
        int pre = 0, tt_tot = 0;
        for (int tt = 0; tt < 256; ++tt) {
          const int vv = eqc[i][tt];
          if (tt < t) pre += vv;
          tt_tot += vv;
        }
        base[i] = run + pre;
        run += tt_tot;
      }
    }
#pragma unroll
    for (int i = 0; i < 12; ++i) {
      float vals[4];
      int r = base[i];
#pragma unroll
      for (int j = 0; j < 4; ++j) {
        const unsigned uu = u[i * 4 + j];
        const float f = att_decode(uu);
        bool keep = false;
        if (uu > T) keep = true;
        else if (uu == T) { keep = (r < need); ++r; }
        vals[j] = keep ? fmaxf(f, 0.0f) : 0.0f;
      }
      float4 o; o.x = vals[0]; o.y = vals[1]; o.z = vals[2]; o.w = vals[3];
      reinterpret_cast<float4*>(row)[t + 256 * i] = o;
    }
  }
}

// ---------------------------------------------------------------------------
extern "C" void kernel_launch(void* const* d_in, const int* in_sizes, int n_in,
                              void* d_out, int out_size, void* d_ws, size_t ws_size,
                              hipStream_t stream) {
  const float* x  = (const float*)d_in[0];
  const float* w0 = (const float*)d_in[1];
  const float* w1 = (const float*)d_in[2];
  float* out = (float*)d_out;
  float* nrm = (float*)d_ws;                       // 48 KiB
  float* h = (float*)((char*)d_ws + 65536);        // 12.58 MiB (if it fits)

  const size_t need = 65536 + (size_t)N_NODES * D_FEAT * 4;

  np_norm_kernel<<<N_NODES / 256, 256, 0, stream>>>(x, w0, w1, nrm);

  if (ws_size >= need) {
    np_h_kernel<<<(N_NODES * D_FEAT / 4 + 255) / 256, 256, 0, stream>>>(
        x, w0, w1, nrm, h);
    np_gemm_kernel<1><<<NBLOCKS, 256, 0, stream>>>(x, w0, w1, nrm, h, out);
  } else {
    np_gemm_kernel<0><<<NBLOCKS, 256, 0, stream>>>(x, w0, w1, nrm, nullptr, out);
  }

  att_topk_kernel<<<N_NODES, 256, 0, stream>>>(out);
}